// Round 1
// 542.649 us; speedup vs baseline: 1.8057x; 1.8057x over previous
//
#include <hip/hip_runtime.h>

#define NN 50000
#define EE 400000
#define NT64 6250          // 64-edge tiles (EE divisible by 64)
#define EGRID 1250         // 5 blocks/CU x 250... : 1250 blocks, exactly 5 tiles each
#define NBLK 782           // node blocks (64 nodes each)
#define SBLK 49            // scan blocks of 1024 elements

typedef __bf16 bf16x8 __attribute__((ext_vector_type(8)));
typedef float f32x4 __attribute__((ext_vector_type(4)));

static __device__ __forceinline__ ushort f2bf(float f) {
    union { float f; unsigned int i; } x; x.f = f;
    unsigned int r = x.i + 0x7fffu + ((x.i >> 16) & 1u);
    return (ushort)(r >> 16);
}
static __device__ __forceinline__ float bf2f(ushort u) {
    union { unsigned int i; float f; } x; x.i = ((unsigned int)u) << 16; return x.f;
}
static __device__ __forceinline__ unsigned pack2(float lo, float hi) {
    return (unsigned)f2bf(lo) | ((unsigned)f2bf(hi) << 16);
}
static __device__ __forceinline__ float fast_tanh(float x) {
    float e = __expf(2.f * x);
    return 1.f - 2.f / (e + 1.f);
}
static __device__ __forceinline__ bf16x8 pk8(float4 f0, float4 f1) {
    union { uint4 u; bf16x8 v; } z;
    z.u = make_uint4(pack2(f0.x, f0.y), pack2(f0.z, f0.w),
                     pack2(f1.x, f1.y), pack2(f1.z, f1.w));
    return z.v;
}
static __device__ __forceinline__ bf16x8 zero8() {
    union { uint4 u; bf16x8 v; } z;
    z.u = make_uint4(0u, 0u, 0u, 0u);
    return z.v;
}

// ---------------- prep: swizzle f32 weights into bf16 MFMA B-fragment order ----------------
__global__ __launch_bounds__(256) void prep_edge_k(
    const float* __restrict__ W1, const float* __restrict__ W2,
    const float* __restrict__ b1, const float* __restrict__ b2,
    ushort* __restrict__ B1P, ushort* __restrict__ B2P,
    float* __restrict__ b1f, float* __restrict__ b2f)
{
    int idx = blockIdx.x * 256 + threadIdx.x;
    if (idx < 10240) {
        int j = idx & 7, n = (idx >> 3) & 63, qk = idx >> 9;
        int kc = qk >> 2, quad = qk & 3;
        int k = kc * 32 + quad * 8 + j;
        B1P[idx] = (k < 144) ? f2bf(W1[k * 64 + n]) : (ushort)0;
    }
    if (idx < 4096) {
        int j = idx & 7, n = (idx >> 3) & 63, qk = idx >> 9;
        int kc = qk >> 2, quad = qk & 3;
        int k = kc * 32 + quad * 8 + j;
        B2P[idx] = f2bf(W2[k * 64 + n]);
    }
    if (idx < 64) { b1f[idx] = b1[idx]; b2f[idx] = b2[idx]; }
}

__global__ __launch_bounds__(256) void prep_node_k(
    const float* __restrict__ Wd1, const float* __restrict__ Wd2,
    const float* __restrict__ bd1, const float* __restrict__ lng,
    const float* __restrict__ lnb, const float* __restrict__ bd2,
    ushort* __restrict__ Wd1P, ushort* __restrict__ Wd2P,
    float* __restrict__ bd1f, float* __restrict__ lngf,
    float* __restrict__ lnbf, float* __restrict__ bd2f)
{
    int idx = blockIdx.x * 256 + threadIdx.x;
    if (idx < 8192) {
        int j = idx & 7, n = (idx >> 3) & 63, qk = idx >> 9;
        int kc = qk >> 2, quad = qk & 3;
        int k = kc * 32 + quad * 8 + j;
        Wd1P[idx] = f2bf(Wd1[k * 64 + n]);
    }
    if (idx < 4096) {
        int j = idx & 7, n = (idx >> 3) & 63, qk = idx >> 9;
        int kc = qk >> 2, quad = qk & 3;
        int k = kc * 32 + quad * 8 + j;
        Wd2P[idx] = f2bf(Wd2[k * 64 + n]);
    }
    if (idx < 64) {
        bd1f[idx] = bd1[idx]; lngf[idx] = lng[idx];
        lnbf[idx] = lnb[idx]; bd2f[idx] = bd2[idx];
    }
}

// ---------------- state: h = (t==0 ? 2*hseq : h + hseq); bf16 mirror ----------------
__global__ __launch_bounds__(256) void state_k(
    float* __restrict__ h, ushort* __restrict__ hb,
    const float* __restrict__ hseq_t, int mode)
{
    int i = blockIdx.x * 256 + threadIdx.x;
    float v = hseq_t[i];
    float r = (mode == 0) ? (2.f * v) : (h[i] + v);
    h[i] = r; hb[i] = f2bf(r);
}

// ---------------- CSR build ----------------
__global__ __launch_bounds__(256) void zero_k(int* __restrict__ p, int n) {
    int i = blockIdx.x * 256 + threadIdx.x;
    if (i < n) p[i] = 0;
}
__global__ __launch_bounds__(256) void zero_f(float* __restrict__ p) {
    int i = blockIdx.x * 256 + threadIdx.x;
    p[i] = 0.f;
}
__global__ __launch_bounds__(256) void hist_k(const int* __restrict__ rows, int* __restrict__ counts) {
    int e = blockIdx.x * 256 + threadIdx.x;
    if (e < EE) atomicAdd(&counts[rows[e]], 1);
}

// parallel exclusive scan, 3 phases (replaces serial single-block scan: carry
// chain forced ~49 dependent iterations on ONE CU)
__global__ __launch_bounds__(256) void scanA_k(
    const int* __restrict__ counts, int* __restrict__ offsets, int* __restrict__ bsum)
{
    __shared__ int wsum[4];
    int tid = threadIdx.x, lane = tid & 63, w = tid >> 6;
    int i4 = blockIdx.x * 1024 + tid * 4;
    int4 v = make_int4(0, 0, 0, 0);
    if (i4 + 3 < NN) v = *(const int4*)(counts + i4);
    else {
        if (i4 < NN) v.x = counts[i4];
        if (i4 + 1 < NN) v.y = counts[i4 + 1];
        if (i4 + 2 < NN) v.z = counts[i4 + 2];
    }
    int s = v.x + v.y + v.z + v.w;
    int x = s;
    for (int off = 1; off < 64; off <<= 1) {
        int y = __shfl_up(x, off);
        if (lane >= off) x += y;
    }
    if (lane == 63) wsum[w] = x;
    __syncthreads();
    int wpre = 0;
    for (int j = 0; j < w; j++) wpre += wsum[j];
    int excl = wpre + x - s;
    int e0 = excl, e1 = e0 + v.x, e2 = e1 + v.y, e3 = e2 + v.z;
    if (i4 + 3 < NN) *(int4*)(offsets + i4) = make_int4(e0, e1, e2, e3);
    else {
        if (i4 < NN) offsets[i4] = e0;
        if (i4 + 1 < NN) offsets[i4 + 1] = e1;
        if (i4 + 2 < NN) offsets[i4 + 2] = e2;
    }
    if (tid == 255) bsum[blockIdx.x] = wpre + x;
}
__global__ __launch_bounds__(64) void scanB_k(const int* __restrict__ bsum, int* __restrict__ bpre) {
    int lane = threadIdx.x;
    int v = (lane < SBLK) ? bsum[lane] : 0;
    int x = v;
    for (int off = 1; off < 64; off <<= 1) {
        int y = __shfl_up(x, off);
        if (lane >= off) x += y;
    }
    if (lane < SBLK) bpre[lane] = x - v;
}
__global__ __launch_bounds__(256) void scanC_k(
    int* __restrict__ offsets, int* __restrict__ cursor, const int* __restrict__ bpre)
{
    int i = blockIdx.x * 256 + threadIdx.x;
    if (i < NN) {
        int o = offsets[i] + bpre[i >> 10];
        offsets[i] = o; cursor[i] = o;
    }
    if (i == 0) offsets[NN] = EE;  // every edge's row is in [0,NN)
}

// fill: counting-sort edges into slot order AND emit sorted row/col indices plus
// bf16-packed edge attrs, so edge_k streams everything contiguously and msg is
// written in CSR-slot order (agg_k becomes fully contiguous, no eslot indirection)
__global__ __launch_bounds__(256) void fill_k(
    const int* __restrict__ rows, const int* __restrict__ cols,
    const float* __restrict__ ea, int* __restrict__ cursor,
    int* __restrict__ rsort, int* __restrict__ csort, ushort* __restrict__ eab)
{
    int e = blockIdx.x * 256 + threadIdx.x;
    if (e < EE) {
        int r = rows[e];
        int p = atomicAdd(&cursor[r], 1);
        if ((unsigned)p < (unsigned)EE) {
            rsort[p] = r; csort[p] = cols[e];
            const float* sp = ea + (size_t)e * 16;
            float4 f0 = ((const float4*)sp)[0], f1 = ((const float4*)sp)[1];
            float4 f2 = ((const float4*)sp)[2], f3 = ((const float4*)sp)[3];
            uint4* dp = (uint4*)(eab + (size_t)p * 16);
            dp[0] = make_uint4(pack2(f0.x, f0.y), pack2(f0.z, f0.w),
                               pack2(f1.x, f1.y), pack2(f1.z, f1.w));
            dp[1] = make_uint4(pack2(f2.x, f2.y), pack2(f2.z, f2.w),
                               pack2(f3.x, f3.y), pack2(f3.z, f3.w));
        }
    }
}

// ---------------- edge MLP: per-lane register gather -> MFMA, zero per-tile barriers ----------------
// A-fragment for 16x16x32 is 8 CONTIGUOUS k-elements per lane: load straight from
// hb[r]/hb[c]/eab as 16B chunks (identical values to the old sA staging).
// sH (L1->L2 handoff) is wave-private (rows wave*16..+15) -> wave_barrier only.
// LDS 29696 B -> 5 blocks/CU (was 51200 -> 3); grid 1250 = exactly 5 tiles/block.
// MODE 0: sorted slots -> msg (CSR order). MODE 1: raw order -> atomicAdd (ws fallback).
template<int MODE>
__global__ __launch_bounds__(256, 5) void edge_k(
    const ushort* __restrict__ hb,
    const int* __restrict__ ridx, const int* __restrict__ cidx,
    const ushort* __restrict__ eab, const float* __restrict__ eaf,
    const ushort* __restrict__ B1P, const ushort* __restrict__ B2P,
    const float* __restrict__ b1f, const float* __restrict__ b2f,
    ushort* __restrict__ msg, float* __restrict__ agg)
{
    __shared__ __attribute__((aligned(16))) ushort sB1[10240];
    __shared__ __attribute__((aligned(16))) ushort sH[64 * 72];   // pad 64->72

    int tid = threadIdx.x;
    int lane = tid & 63, wave = tid >> 6;
    int m = lane & 15, quad = lane >> 4;

    for (int i = tid; i < 10240 / 8; i += 256) ((uint4*)sB1)[i] = ((const uint4*)B1P)[i];
    bf16x8 b2r[2][4];
    for (int kc = 0; kc < 2; kc++)
        for (int nt = 0; nt < 4; nt++)
            b2r[kc][nt] = *(const bf16x8*)(B2P + ((kc * 4 + quad) * 64 + nt * 16 + m) * 8);
    float b1v[4], b2v[4];
    for (int nt = 0; nt < 4; nt++) { b1v[nt] = b1f[nt * 16 + m]; b2v[nt] = b2f[nt * 16 + m]; }
    __syncthreads();   // weights staged (only barrier in the kernel)

    ushort* sHw = sH + wave * 1152;   // wave-private 16x72 slice
    int sl = wave * 16 + m;           // this lane's edge row within the tile

    int spf = blockIdx.x * 64 + sl;
    int r_n = ridx[spf], c_n = cidx[spf];   // index prefetch

    for (int t = blockIdx.x; t < NT64; t += EGRID) {
        int s = t * 64 + sl;
        int r = r_n, c = c_n;

        bf16x8 a[5];
        a[0] = *(const bf16x8*)(hb + (size_t)r * 64 + quad * 8);
        a[1] = *(const bf16x8*)(hb + (size_t)r * 64 + 32 + quad * 8);
        a[2] = *(const bf16x8*)(hb + (size_t)c * 64 + quad * 8);
        a[3] = *(const bf16x8*)(hb + (size_t)c * 64 + 32 + quad * 8);
        a[4] = zero8();                      // k=144..159 zero-pad (quads 2,3)
        if (MODE == 0) {
            if (quad < 2) a[4] = *(const bf16x8*)(eab + (size_t)s * 16 + quad * 8);
        } else {
            if (quad < 2) {
                const float* sp = eaf + (size_t)s * 16 + quad * 8;
                float4 f0 = ((const float4*)sp)[0], f1 = ((const float4*)sp)[1];
                a[4] = pk8(f0, f1);
            }
        }

        // prefetch next tile's indices (independent of this tile's chain)
        int tn = t + EGRID; if (tn >= NT64) tn = t;
        int sn = tn * 64 + sl;
        r_n = ridx[sn]; c_n = cidx[sn];

        // layer 1: [16 edges x 160] @ [160 x 64]
        f32x4 acc[4];
        #pragma unroll
        for (int nt = 0; nt < 4; nt++) acc[nt] = (f32x4){0.f, 0.f, 0.f, 0.f};
        #pragma unroll
        for (int kc = 0; kc < 5; kc++) {
            #pragma unroll
            for (int nt = 0; nt < 4; nt++) {
                bf16x8 b = *(const bf16x8*)(sB1 + ((kc * 4 + quad) * 64 + nt * 16 + m) * 8);
                acc[nt] = __builtin_amdgcn_mfma_f32_16x16x32_bf16(a[kc], b, acc[nt], 0, 0, 0);
            }
        }

        __builtin_amdgcn_wave_barrier();   // prior-iter sH reads stay before these writes
        #pragma unroll
        for (int nt = 0; nt < 4; nt++) {
            int colid = nt * 16 + m;
            float bb = b1v[nt];
            #pragma unroll
            for (int rr = 0; rr < 4; rr++) {
                float v = acc[nt][rr] + bb;
                v = v > 0.f ? v : 0.f;
                sHw[(quad * 4 + rr) * 72 + colid] = f2bf(v);
            }
        }
        __builtin_amdgcn_wave_barrier();   // writes before reads (same-wave DS is in-order)

        // layer 2: [16 x 64] @ [64 x 64], B from registers
        f32x4 acc2[4];
        #pragma unroll
        for (int nt = 0; nt < 4; nt++) acc2[nt] = (f32x4){0.f, 0.f, 0.f, 0.f};
        #pragma unroll
        for (int kc = 0; kc < 2; kc++) {
            bf16x8 av = *(const bf16x8*)(sHw + m * 72 + kc * 32 + quad * 8);
            #pragma unroll
            for (int nt = 0; nt < 4; nt++) {
                acc2[nt] = __builtin_amdgcn_mfma_f32_16x16x32_bf16(av, b2r[kc][nt], acc2[nt], 0, 0, 0);
            }
        }

        int rr4[4];
        if (MODE == 1) {
            #pragma unroll
            for (int rr = 0; rr < 4; rr++) rr4[rr] = ridx[t * 64 + wave * 16 + quad * 4 + rr];
        }
        #pragma unroll
        for (int nt = 0; nt < 4; nt++) {
            int colid = nt * 16 + m;
            float bb = b2v[nt];
            #pragma unroll
            for (int rr = 0; rr < 4; rr++) {
                float v = acc2[nt][rr] + bb;
                int so = t * 64 + wave * 16 + quad * 4 + rr;
                if (MODE == 0) {
                    msg[(size_t)so * 64 + colid] = f2bf(v);
                } else {
                    atomicAdd(&agg[(size_t)rr4[rr] * 64 + colid], v);
                }
            }
        }
    }
}

// ---------------- aggregate: msg is slot-ordered -> fully contiguous reads ----------------
__global__ __launch_bounds__(256) void agg_k(
    const ushort* __restrict__ msg, const int* __restrict__ offsets,
    float* __restrict__ agg)
{
    int gw = (blockIdx.x * 256 + threadIdx.x) >> 6;
    int lane = threadIdx.x & 63;
    int beg = offsets[gw], end = offsets[gw + 1];
    beg = beg < 0 ? 0 : beg;
    end = end > EE ? EE : end;
    float a = 0.f;
    int i = beg;
    for (; i + 4 <= end; i += 4) {
        a += bf2f(msg[(size_t)i * 64 + lane]);
        a += bf2f(msg[(size_t)(i + 1) * 64 + lane]);
        a += bf2f(msg[(size_t)(i + 2) * 64 + lane]);
        a += bf2f(msg[(size_t)(i + 3) * 64 + lane]);
    }
    for (; i < end; i++) a += bf2f(msg[(size_t)i * 64 + lane]);
    agg[(size_t)gw * 64 + lane] = a;
}

// ---------------- node MLP: register gather (hb + agg) -> MFMA; LN in-register ----------------
// LDS 33792 B -> 4 blocks/CU: all 782 blocks resident in one scheduling wave.
// sX handoff is wave-private -> wave_barrier replaces the second __syncthreads.
__global__ __launch_bounds__(256, 4) void node_k(
    float* __restrict__ h, ushort* __restrict__ hbm,
    const float* __restrict__ agg,
    const ushort* __restrict__ Wd1P, const ushort* __restrict__ Wd2P,
    const float* __restrict__ bd1f, const float* __restrict__ lngf,
    const float* __restrict__ lnbf, const float* __restrict__ bd2f)
{
    __shared__ __attribute__((aligned(16))) ushort sB1[8192];
    __shared__ __attribute__((aligned(16))) ushort sB2[4096];
    __shared__ __attribute__((aligned(16))) ushort sX[64 * 72];
    int tid = threadIdx.x;
    int lane = tid & 63, wave = tid >> 6;
    int m = lane & 15, quad = lane >> 4;
    int nbase = blockIdx.x * 64;

    for (int i = tid; i < 8192 / 8; i += 256) ((uint4*)sB1)[i] = ((const uint4*)Wd1P)[i];
    for (int i = tid; i < 4096 / 8; i += 256) ((uint4*)sB2)[i] = ((const uint4*)Wd2P)[i];
    float gA[4], bA[4], d1[4], d2[4];
    for (int nt = 0; nt < 4; nt++) {
        int f = nt * 16 + m;
        d1[nt] = bd1f[f]; gA[nt] = lngf[f]; bA[nt] = lnbf[f]; d2[nt] = bd2f[f];
    }
    __syncthreads();

    // per-lane A fragments: [h(bf16 mirror, identical values to old f2bf(h)) | agg(f32->bf16)]
    int n = nbase + wave * 16 + m;
    if (n > NN - 1) n = NN - 1;                  // clamped rows are compute-only
    bf16x8 A[4];
    A[0] = *(const bf16x8*)(hbm + (size_t)n * 64 + quad * 8);
    A[1] = *(const bf16x8*)(hbm + (size_t)n * 64 + 32 + quad * 8);
    {
        const float* ap = agg + (size_t)n * 64 + quad * 8;
        A[2] = pk8(((const float4*)ap)[0], ((const float4*)ap)[1]);
        const float* ap2 = agg + (size_t)n * 64 + 32 + quad * 8;
        A[3] = pk8(((const float4*)ap2)[0], ((const float4*)ap2)[1]);
    }

    f32x4 acc[4];
    #pragma unroll
    for (int nt = 0; nt < 4; nt++) acc[nt] = (f32x4){0.f, 0.f, 0.f, 0.f};
    #pragma unroll
    for (int kc = 0; kc < 4; kc++) {
        #pragma unroll
        for (int nt = 0; nt < 4; nt++) {
            bf16x8 b = *(const bf16x8*)(sB1 + ((kc * 4 + quad) * 64 + nt * 16 + m) * 8);
            acc[nt] = __builtin_amdgcn_mfma_f32_16x16x32_bf16(A[kc], b, acc[nt], 0, 0, 0);
        }
    }

    float xs[4][4];
    #pragma unroll
    for (int nt = 0; nt < 4; nt++)
        #pragma unroll
        for (int r = 0; r < 4; r++)
            xs[nt][r] = acc[nt][r] + d1[nt];

    ushort* sXw = sX + wave * 1152;
    #pragma unroll
    for (int r = 0; r < 4; r++) {
        float s1 = 0.f, s2 = 0.f;
        #pragma unroll
        for (int nt = 0; nt < 4; nt++) { float v = xs[nt][r]; s1 += v; s2 += v * v; }
        for (int off = 1; off < 16; off <<= 1) {
            s1 += __shfl_xor(s1, off);
            s2 += __shfl_xor(s2, off);
        }
        float mean = s1 * (1.f / 64.f);
        float var = fmaxf(s2 * (1.f / 64.f) - mean * mean, 0.f);
        float rstd = rsqrtf(var + 1e-5f);
        #pragma unroll
        for (int nt = 0; nt < 4; nt++) {
            float xn = (xs[nt][r] - mean) * rstd * gA[nt] + bA[nt];
            float sl = xn / (1.f + __expf(-xn));
            sXw[(quad * 4 + r) * 72 + nt * 16 + m] = f2bf(sl);
        }
    }
    __builtin_amdgcn_wave_barrier();   // sX slice is wave-private; same-wave DS is in-order

    f32x4 acc2[4];
    #pragma unroll
    for (int nt = 0; nt < 4; nt++) acc2[nt] = (f32x4){0.f, 0.f, 0.f, 0.f};
    #pragma unroll
    for (int kc = 0; kc < 2; kc++) {
        bf16x8 av = *(const bf16x8*)(sXw + m * 72 + kc * 32 + quad * 8);
        #pragma unroll
        for (int nt = 0; nt < 4; nt++) {
            bf16x8 b = *(const bf16x8*)(sB2 + ((kc * 4 + quad) * 64 + nt * 16 + m) * 8);
            acc2[nt] = __builtin_amdgcn_mfma_f32_16x16x32_bf16(av, b, acc2[nt], 0, 0, 0);
        }
    }

    // RMW h: ONLY in-range slots write (tail duplicates racing the RMW was the R6 bug)
    #pragma unroll
    for (int r = 0; r < 4; r++) {
        int g = nbase + wave * 16 + quad * 4 + r;
        if (g < NN) {
            #pragma unroll
            for (int nt = 0; nt < 4; nt++) {
                int f = nt * 16 + m;
                float y = fast_tanh(acc2[nt][r] + d2[nt]);
                float hn = h[(size_t)g * 64 + f] + 0.5f * y;
                h[(size_t)g * 64 + f] = hn;
                hbm[(size_t)g * 64 + f] = f2bf(hn);
            }
        }
    }
}

// ---------------- disagreement (f32) + final (f32) ----------------
__global__ __launch_bounds__(256) void dis_k(
    const float* __restrict__ h, const int* __restrict__ rows,
    const int* __restrict__ cols, float* __restrict__ outp)
{
    int tid = threadIdx.x;
    int e = blockIdx.x * 16 + (tid >> 4);
    int l16 = tid & 15;
    int r = rows[e], c = cols[e];
    float4 a = *(const float4*)(h + (size_t)r * 64 + l16 * 4);
    float4 b = *(const float4*)(h + (size_t)c * 64 + l16 * 4);
    float dx = a.x - b.x, dy = a.y - b.y, dz = a.z - b.z, dw = a.w - b.w;
    float s = dx * dx + dy * dy + dz * dz + dw * dw;
    for (int off = 1; off < 16; off <<= 1) s += __shfl_xor(s, off);
    if (l16 == 0) outp[e] = (s < 1e4f ? s : 1e4f);
}

__global__ __launch_bounds__(256) void final_k(const float* __restrict__ h, float* __restrict__ out) {
    int i = blockIdx.x * 256 + threadIdx.x;
    out[i] = h[i];
}

extern "C" void kernel_launch(void* const* d_in, const int* in_sizes, int n_in,
                              void* d_out, int out_size, void* d_ws, size_t ws_size,
                              hipStream_t stream) {
    const float* h_seq = (const float*)d_in[0];
    const float* eattr = (const float*)d_in[1];
    const float* W1 = (const float*)d_in[2];
    const float* b1 = (const float*)d_in[3];
    const float* W2 = (const float*)d_in[4];
    const float* b2 = (const float*)d_in[5];
    const float* Wd1 = (const float*)d_in[6];
    const float* bd1 = (const float*)d_in[7];
    const float* lng = (const float*)d_in[8];
    const float* lnb = (const float*)d_in[9];
    const float* Wd2 = (const float*)d_in[10];
    const float* bd2 = (const float*)d_in[11];
    const int* ei = (const int*)d_in[12];
    float* out = (float*)d_out;

    char* wsp = (char*)d_ws;
    size_t used = 0;
    auto carve = [&](size_t b) {
        void* p = (void*)(wsp + used);
        used += (b + 255) & ~(size_t)255;
        return p;
    };
    // fallback-critical buffers first, msg last
    float* h      = (float*)carve((size_t)NN * 64 * 4);
    ushort* hb    = (ushort*)carve((size_t)NN * 64 * 2);
    float* agg    = (float*)carve((size_t)NN * 64 * 4);
    ushort* B1P   = (ushort*)carve(10240 * 2);
    ushort* B2P   = (ushort*)carve(4096 * 2);
    ushort* Wd1P  = (ushort*)carve(8192 * 2);
    ushort* Wd2P  = (ushort*)carve(4096 * 2);
    float* b1f    = (float*)carve(256);
    float* b2f    = (float*)carve(256);
    float* bd1f   = (float*)carve(256);
    float* lngf   = (float*)carve(256);
    float* lnbf   = (float*)carve(256);
    float* bd2f   = (float*)carve(256);
    int* counts   = (int*)carve((size_t)NN * 4);
    int* offsets  = (int*)carve((size_t)(NN + 1) * 4);
    int* cursor   = (int*)carve((size_t)NN * 4);
    int* bsum     = (int*)carve(256);
    int* bpre     = (int*)carve(256);
    int* rsort    = (int*)carve((size_t)EE * 4);
    int* csort    = (int*)carve((size_t)EE * 4);
    ushort* eab   = (ushort*)carve((size_t)EE * 16 * 2);
    ushort* msg   = (ushort*)carve((size_t)EE * 64 * 2);
    const bool full = (used <= ws_size);

    prep_edge_k<<<40, 256, 0, stream>>>(W1, W2, b1, b2, B1P, B2P, b1f, b2f);
    prep_node_k<<<32, 256, 0, stream>>>(Wd1, Wd2, bd1, lng, lnb, bd2, Wd1P, Wd2P, bd1f, lngf, lnbf, bd2f);

    for (int t = 0; t < 2; t++) {
        const int* rows = ei + (size_t)t * 2 * EE;
        const int* cols = rows + EE;
        const float* eat = eattr + (size_t)t * EE * 16;
        state_k<<<12500, 256, 0, stream>>>(h, hb, h_seq + (size_t)t * NN * 64, t);
        if (full) {
            zero_k<<<196, 256, 0, stream>>>(counts, NN);
            hist_k<<<1563, 256, 0, stream>>>(rows, counts);
            scanA_k<<<SBLK, 256, 0, stream>>>(counts, offsets, bsum);
            scanB_k<<<1, 64, 0, stream>>>(bsum, bpre);
            scanC_k<<<196, 256, 0, stream>>>(offsets, cursor, bpre);
            fill_k<<<1563, 256, 0, stream>>>(rows, cols, eat, cursor, rsort, csort, eab);
        }
        for (int s = 0; s < 2; s++) {
            if (full) {
                edge_k<0><<<EGRID, 256, 0, stream>>>(hb, rsort, csort, eab, (const float*)0,
                                                     B1P, B2P, b1f, b2f, msg, agg);
                agg_k<<<12500, 256, 0, stream>>>(msg, offsets, agg);
            } else {
                zero_f<<<12500, 256, 0, stream>>>(agg);
                edge_k<1><<<EGRID, 256, 0, stream>>>(hb, rows, cols, (const ushort*)0, eat,
                                                     B1P, B2P, b1f, b2f, msg, agg);
            }
            node_k<<<NBLK, 256, 0, stream>>>(h, hb, agg, Wd1P, Wd2P,
                                             bd1f, lngf, lnbf, bd2f);
        }
        dis_k<<<25000, 256, 0, stream>>>(h, rows, cols, out + (size_t)NN * 64 + (size_t)t * EE);
    }
    final_k<<<12500, 256, 0, stream>>>(h, out);
}